// Round 1
// baseline (215.477 us; speedup 1.0000x reference)
//
#include <hip/hip_runtime.h>

// CAMixer agent-attention, fused per-window (8x8), fp32.
//
// Algebra (exact refactor):
//   agent   = conv(pool(x), Wq)              (pool/conv commute; pool rows sum to 1)
//   k-logit[p][l] = xw[l]·gk[p] + bkd[p],  gk = xp @ Mk + bk2,  Mk = Wq^T Wk
//   q-logit[l][p] = xw[l]·gq[p] + bqd[p],  gq = xp @ Mq + bq2,  Mq = Wq^T Wq
//   agent_v = (a_attn @ xw) @ Wv^T + bv      (softmax rows sum to 1)
// => q,k,v convs never materialized: ~0.86 MFLOP/window instead of ~7.5.

constexpr int C_   = 96;
constexpr int Himg = 192;
constexpr int Wimg = 192;
constexpr int HWp  = Himg * Wimg;   // 36864
constexpr int Bn   = 8;
constexpr int NWIN = 24;            // windows per spatial dim
constexpr int Lw   = 64;            // tokens per window
constexpr int Pp   = 7;             // agent tokens
constexpr int XLD  = 65;            // padded LDS stride (65 mod 32 == 1 -> conflict-free both axes)

// ---------------- precompute (weights only, trivial cost) ----------------

__global__ void precompute_mats(const float* __restrict__ Wq,
                                const float* __restrict__ Wk,
                                const float* __restrict__ Wv,
                                float* __restrict__ Mk,
                                float* __restrict__ Mq,
                                float* __restrict__ WvT)
{
    const int c  = blockIdx.x;   // 0..95 (inner/contraction index of Gram)
    const int cp = threadIdx.x;  // 0..95
    float ak = 0.f, aq = 0.f;
    for (int a = 0; a < C_; ++a) {
        const float wq = Wq[a * C_ + c];
        ak = fmaf(wq, Wk[a * C_ + cp], ak);
        aq = fmaf(wq, Wq[a * C_ + cp], aq);
    }
    Mk[c * C_ + cp]  = ak;                 // Mk[c][c'] = sum_a Wq[a][c] Wk[a][c']
    Mq[c * C_ + cp]  = aq;
    WvT[c * C_ + cp] = Wv[cp * C_ + c];    // WvT[c][o] = Wv[o][c]
}

__global__ void precompute_vecs(const float* __restrict__ Wq,
                                const float* __restrict__ Wk,
                                const float* __restrict__ bq,
                                const float* __restrict__ bk,
                                float* __restrict__ uk,  float* __restrict__ uq,
                                float* __restrict__ bk2, float* __restrict__ bq2,
                                float* __restrict__ scal)
{
    const int c = threadIdx.x;   // 0..95
    float a_uk = 0.f, a_uq = 0.f, a_bk2 = 0.f, a_bq2 = 0.f;
    for (int a = 0; a < C_; ++a) {
        const float wqc = Wq[a * C_ + c];
        a_uk  = fmaf(wqc, bk[a], a_uk);        // uk  = Wq^T bk
        a_uq  = fmaf(wqc, bq[a], a_uq);        // uq  = Wq^T bq
        a_bk2 = fmaf(bq[a], Wk[a * C_ + c], a_bk2);  // bk2 = bq @ Wk
        a_bq2 = fmaf(bq[a], Wq[a * C_ + c], a_bq2);  // bq2 = bq @ Wq
    }
    uk[c] = a_uk; uq[c] = a_uq; bk2[c] = a_bk2; bq2[c] = a_bq2;
    if (c == 0) {
        float sk = 0.f, sq = 0.f;
        for (int a = 0; a < C_; ++a) { sk += bq[a] * bk[a]; sq += bq[a] * bq[a]; }
        scal[0] = sk; scal[1] = sq;
    }
}

// ---------------- main fused kernel: one block per window ----------------

__global__ __launch_bounds__(256) void camixer_main(
    const float* __restrict__ x,    // [B,C,H,W]
    const float* __restrict__ bv,   // [C]
    const float* __restrict__ Mk,
    const float* __restrict__ Mq,
    const float* __restrict__ WvT,
    const float* __restrict__ uk,
    const float* __restrict__ uq,
    const float* __restrict__ bk2,
    const float* __restrict__ bq2,
    const float* __restrict__ scal,
    float* __restrict__ out)
{
    __shared__ float xw[C_][XLD];        // x window, [c][l]   (~25 KB)
    __shared__ float xp[Pp][C_];         // pooled x, later reused as xv
    __shared__ float gk[Pp][C_];
    __shared__ float gq[Pp][C_];
    __shared__ float attn[Pp][Lw];       // a_attn
    __shared__ float av[Pp][C_];         // agent_v
    __shared__ float qat[Lw][8];         // q_attn (padded)
    __shared__ float red[4][Pp][Lw];     // c-split partial logits
    __shared__ float bkd[Pp], bqd[Pp];

    const int t  = threadIdx.x;
    const int n  = blockIdx.x;
    const int b  = n / (NWIN * NWIN);
    const int r  = n % (NWIN * NWIN);
    const int h0 = (r / NWIN) * 8;
    const int w0 = (r % NWIN) * 8;
    const int base = b * C_ * HWp + h0 * Wimg + w0;   // x[b][0][h0][w0]

    // P0: gather x window -> LDS (float4 global loads, 32B runs per window row)
    {
        const float4* x4 = reinterpret_cast<const float4*>(x);
        for (int idx = t; idx < C_ * 16; idx += 256) {
            const int c   = idx >> 4;
            const int q4  = idx & 15;
            const int dh  = q4 >> 1;
            const int dw4 = (q4 & 1) << 2;
            const float4 v = x4[(base + c * HWp + dh * Wimg + dw4) >> 2];
            const int l0 = dh * 8 + dw4;
            xw[c][l0 + 0] = v.x; xw[c][l0 + 1] = v.y;
            xw[c][l0 + 2] = v.z; xw[c][l0 + 3] = v.w;
        }
    }
    __syncthreads();

    // P1: adaptive pool 64 -> 7 (all segments are 10 long, weight 0.1)
    for (int idx = t; idx < Pp * C_; idx += 256) {
        const int p = idx / C_, c = idx % C_;
        const int s = (p * Lw) / Pp;       // {0,9,18,27,36,45,54}
        float acc = 0.f;
        #pragma unroll
        for (int j = 0; j < 10; ++j) acc += xw[c][s + j];
        xp[p][c] = acc * 0.1f;
    }
    __syncthreads();

    // P2: gk = xp@Mk + bk2, gq = xp@Mq + bq2, bias dots (p-register-blocked;
    //     each Mk/Mq element read exactly once per block, straight from L2)
    if (t < 96) {
        const int cp = t;
        float acc[Pp] = {};
        for (int c = 0; c < C_; ++c) {
            const float m = Mk[c * C_ + cp];
            #pragma unroll
            for (int p = 0; p < Pp; ++p) acc[p] = fmaf(xp[p][c], m, acc[p]);
        }
        const float b2 = bk2[cp];
        #pragma unroll
        for (int p = 0; p < Pp; ++p) gk[p][cp] = acc[p] + b2;
    } else if (t < 192) {
        const int cp = t - 96;
        float acc[Pp] = {};
        for (int c = 0; c < C_; ++c) {
            const float m = Mq[c * C_ + cp];
            #pragma unroll
            for (int p = 0; p < Pp; ++p) acc[p] = fmaf(xp[p][c], m, acc[p]);
        }
        const float b2 = bq2[cp];
        #pragma unroll
        for (int p = 0; p < Pp; ++p) gq[p][cp] = acc[p] + b2;
    } else if (t < 192 + 14) {
        const int j = t - 192;             // 0..13
        const int p = j % 7;
        const float* u = (j < 7) ? uk : uq;
        float acc = 0.f;
        for (int c = 0; c < C_; ++c) acc = fmaf(xp[p][c], u[c], acc);
        if (j < 7) bkd[p] = acc + scal[0]; else bqd[p] = acc + scal[1];
    }
    __syncthreads();

    // P3: k-logits [7][64] (c-loop split 4 ways across waves) + wave softmax over l
    {
        const int l = t & 63, g = t >> 6;
        const int c0 = g * 24;
        float acc[Pp] = {};
        for (int c = c0; c < c0 + 24; ++c) {
            const float xv_ = xw[c][l];
            #pragma unroll
            for (int p = 0; p < Pp; ++p) acc[p] = fmaf(xv_, gk[p][c], acc[p]);
        }
        #pragma unroll
        for (int p = 0; p < Pp; ++p) red[g][p][l] = acc[p];
    }
    __syncthreads();
    {
        const int w = t >> 6, l = t & 63;
        for (int p = w; p < Pp; p += 4) {
            float v = red[0][p][l] + red[1][p][l] + red[2][p][l] + red[3][p][l] + bkd[p];
            float mx = v;
            #pragma unroll
            for (int off = 32; off; off >>= 1) mx = fmaxf(mx, __shfl_xor(mx, off));
            const float e = __expf(v - mx);
            float s = e;
            #pragma unroll
            for (int off = 32; off; off >>= 1) s += __shfl_xor(s, off);
            attn[p][l] = e / s;
        }
    }
    __syncthreads();

    // P4: xv = a_attn @ xw  [7][96]  (stored into xp, which is dead now)
    if (t < 96) {
        const int c = t;
        float acc[Pp] = {};
        for (int l = 0; l < Lw; ++l) {
            const float xv_ = xw[c][l];
            #pragma unroll
            for (int p = 0; p < Pp; ++p) acc[p] = fmaf(attn[p][l], xv_, acc[p]);
        }
        #pragma unroll
        for (int p = 0; p < Pp; ++p) xp[p][c] = acc[p];
    }
    __syncthreads();

    // P5: agent_v = xv @ WvT + bv  [7][96]
    if (t < 96) {
        const int o = t;
        float acc[Pp] = {};
        for (int c = 0; c < C_; ++c) {
            const float wv = WvT[c * C_ + o];
            #pragma unroll
            for (int p = 0; p < Pp; ++p) acc[p] = fmaf(xp[p][c], wv, acc[p]);
        }
        const float bvo = bv[o];
        #pragma unroll
        for (int p = 0; p < Pp; ++p) av[p][o] = acc[p] + bvo;
    }
    __syncthreads();

    // P6: q-logits [64][7] + per-thread softmax over p
    {
        const int l = t & 63, g = t >> 6;
        const int c0 = g * 24;
        float acc[Pp] = {};
        for (int c = c0; c < c0 + 24; ++c) {
            const float xv_ = xw[c][l];
            #pragma unroll
            for (int p = 0; p < Pp; ++p) acc[p] = fmaf(xv_, gq[p][c], acc[p]);
        }
        #pragma unroll
        for (int p = 0; p < Pp; ++p) red[g][p][l] = acc[p];
    }
    __syncthreads();
    if (t < 64) {
        const int l = t;
        float v[Pp];
        float mx = -1e30f;
        #pragma unroll
        for (int p = 0; p < Pp; ++p) {
            v[p] = red[0][p][l] + red[1][p][l] + red[2][p][l] + red[3][p][l] + bqd[p];
            mx = fmaxf(mx, v[p]);
        }
        float s = 0.f;
        #pragma unroll
        for (int p = 0; p < Pp; ++p) { v[p] = __expf(v[p] - mx); s += v[p]; }
        const float inv = 1.f / s;
        #pragma unroll
        for (int p = 0; p < Pp; ++p) qat[l][p] = v[p] * inv;
    }
    __syncthreads();

    // P7: f = q_attn @ agent_v, scatter to out[b][o][h0+dh][w0+dw]
    {
        const int l = t & 63, g = t >> 6;
        float qa[Pp];
        #pragma unroll
        for (int p = 0; p < Pp; ++p) qa[p] = qat[l][p];
        const int dh = l >> 3, dw = l & 7;
        const int obase = b * C_ * HWp + (h0 + dh) * Wimg + (w0 + dw);
        for (int j = 0; j < 24; ++j) {
            const int o = g + 4 * j;       // o wave-uniform -> av reads broadcast
            float acc = 0.f;
            #pragma unroll
            for (int p = 0; p < Pp; ++p) acc = fmaf(qa[p], av[p][o], acc);
            out[obase + o * HWp] = acc;
        }
    }
}

// ---------------- launch ----------------

extern "C" void kernel_launch(void* const* d_in, const int* in_sizes, int n_in,
                              void* d_out, int out_size, void* d_ws, size_t ws_size,
                              hipStream_t stream)
{
    const float* x  = (const float*)d_in[0];
    const float* Wv = (const float*)d_in[1];
    const float* bv = (const float*)d_in[2];
    const float* Wq = (const float*)d_in[3];
    const float* bq = (const float*)d_in[4];
    const float* Wk = (const float*)d_in[5];
    const float* bk = (const float*)d_in[6];
    float* out = (float*)d_out;

    float* ws   = (float*)d_ws;
    float* Mk   = ws;                 // 9216
    float* Mq   = ws + 9216;          // 9216
    float* WvT  = ws + 18432;         // 9216
    float* uk   = ws + 27648;         // 96
    float* uq   = ws + 27744;         // 96
    float* bk2  = ws + 27840;         // 96
    float* bq2  = ws + 27936;         // 96
    float* scal = ws + 28032;         // 2

    hipLaunchKernelGGL(precompute_mats, dim3(C_), dim3(C_), 0, stream,
                       Wq, Wk, Wv, Mk, Mq, WvT);
    hipLaunchKernelGGL(precompute_vecs, dim3(1), dim3(C_), 0, stream,
                       Wq, Wk, bq, bk, uk, uq, bk2, bq2, scal);
    hipLaunchKernelGGL(camixer_main, dim3(Bn * NWIN * NWIN), dim3(256), 0, stream,
                       x, bv, Mk, Mq, WvT, uk, uq, bk2, bq2, scal, out);
}

// Round 2
// 213.543 us; speedup vs baseline: 1.0091x; 1.0091x over previous
//
#include <hip/hip_runtime.h>

// CAMixer agent-attention, fused per-window (8x8), fp32.  v2:
//  - LDS lifetime-aliased unions -> 36.2KB -> 4 blocks/CU (was 3)
//  - p-aligned-wave logit phases, softmax in-register (no `red`, one less barrier)
//  - full-256-thread P4/P5 task decomposition
//  - float4 (b128) LDS broadcasts everywhere
//  - bijective XCD swizzle: 4608 = 8 XCDs x 576 (one batch image per XCD)
//
// Algebra (exact refactor, verified round 1):
//   agent   = conv(pool(x), Wq)              (pool/conv commute; pool rows sum to 1)
//   k-logit[p][l] = xw[l]·gk[p] + bkd[p],  gk = xp @ Mk + bk2,  Mk = Wq^T Wk
//   q-logit[l][p] = xw[l]·gq[p] + bqd[p],  gq = xp @ Mq + bq2,  Mq = Wq^T Wq
//   agent_v = (a_attn @ xw) @ Wv^T + bv      (softmax rows sum to 1)

constexpr int C_   = 96;
constexpr int Wimg = 192;
constexpr int HWp  = 192 * 192;     // 36864
constexpr int NWIN = 24;            // windows per spatial dim
constexpr int Lw   = 64;            // tokens per window
constexpr int Pp   = 7;             // agent tokens
constexpr int XLD  = 65;            // padded LDS stride for xw

// ---------------- precompute (weights only, trivial cost) ----------------

__global__ void precompute_mats(const float* __restrict__ Wq,
                                const float* __restrict__ Wk,
                                float* __restrict__ Mk,
                                float* __restrict__ Mq)
{
    const int c  = blockIdx.x;   // contraction index of Gram
    const int cp = threadIdx.x;
    float ak = 0.f, aq = 0.f;
    for (int a = 0; a < C_; ++a) {
        const float wq = Wq[a * C_ + c];
        ak = fmaf(wq, Wk[a * C_ + cp], ak);
        aq = fmaf(wq, Wq[a * C_ + cp], aq);
    }
    Mk[c * C_ + cp] = ak;            // Mk[c][c'] = sum_a Wq[a][c] Wk[a][c']
    Mq[c * C_ + cp] = aq;
}

__global__ void precompute_vecs(const float* __restrict__ Wq,
                                const float* __restrict__ Wk,
                                const float* __restrict__ bq,
                                const float* __restrict__ bk,
                                float* __restrict__ uk,  float* __restrict__ uq,
                                float* __restrict__ bk2, float* __restrict__ bq2,
                                float* __restrict__ scal)
{
    const int c = threadIdx.x;
    float a_uk = 0.f, a_uq = 0.f, a_bk2 = 0.f, a_bq2 = 0.f;
    for (int a = 0; a < C_; ++a) {
        const float wqc = Wq[a * C_ + c];
        a_uk  = fmaf(wqc, bk[a], a_uk);              // uk  = Wq^T bk
        a_uq  = fmaf(wqc, bq[a], a_uq);              // uq  = Wq^T bq
        a_bk2 = fmaf(bq[a], Wk[a * C_ + c], a_bk2);  // bk2 = bq @ Wk
        a_bq2 = fmaf(bq[a], Wq[a * C_ + c], a_bq2);  // bq2 = bq @ Wq
    }
    uk[c] = a_uk; uq[c] = a_uq; bk2[c] = a_bk2; bq2[c] = a_bq2;
    if (c == 0) {
        float sk = 0.f, sq = 0.f;
        for (int a = 0; a < C_; ++a) { sk += bq[a] * bk[a]; sq += bq[a] * bq[a]; }
        scal[0] = sk; scal[1] = sq;
    }
}

// ---------------- main fused kernel: one block per window ----------------

__global__ __launch_bounds__(256, 4) void camixer_main(
    const float* __restrict__ x,    // [B,C,H,W]
    const float* __restrict__ Wv,   // [C,C] row o = output channel
    const float* __restrict__ bv,   // [C]
    const float* __restrict__ Mk,
    const float* __restrict__ Mq,
    const float* __restrict__ uk,
    const float* __restrict__ uq,
    const float* __restrict__ bk2,
    const float* __restrict__ bq2,
    const float* __restrict__ scal,
    float* __restrict__ out)
{
    // LDS: 6240 + 768 + 1344 + 672 + 16 floats = 36,160 B -> 4 blocks/CU
    __shared__ __align__(16) float xw[C_][XLD];      // x window [c][l], persistent
    __shared__ __align__(16) float Bu[768];          // union: xp[7][96] -> attn[7][64] -> avT[96][8]
    __shared__ __align__(16) float gkq[2][Pp][C_];   // gk (0), gq (1)
    __shared__ __align__(16) float Du[672];          // union: xv[7][96] -> qraw/qat[64][9]
    __shared__ float bkd[8], bqd[8];

    const int t = threadIdx.x;
    // bijective XCD swizzle: XCD (bid%8) gets contiguous window range = one batch image
    const int wid = ((blockIdx.x & 7) * 576) + (blockIdx.x >> 3);
    const int b  = wid / (NWIN * NWIN);
    const int r  = wid % (NWIN * NWIN);
    const int h0 = (r / NWIN) * 8;
    const int w0 = (r % NWIN) * 8;
    const int base = b * C_ * HWp + h0 * Wimg + w0;

    // P0: gather x window -> LDS (float4 global loads)
    {
        const float4* x4 = reinterpret_cast<const float4*>(x);
        #pragma unroll
        for (int it = 0; it < 6; ++it) {
            const int idx = t + it * 256;          // 1536 = 96c x 16 quads
            const int c = idx >> 4, q4 = idx & 15;
            const int dh = q4 >> 1, dw4 = (q4 & 1) << 2;
            const float4 v = x4[(base + c * HWp + dh * Wimg + dw4) >> 2];
            const int l0 = dh * 8 + dw4;
            xw[c][l0 + 0] = v.x; xw[c][l0 + 1] = v.y;
            xw[c][l0 + 2] = v.z; xw[c][l0 + 3] = v.w;
        }
    }
    __syncthreads();

    // P1: adaptive pool 64 -> 7 (all segments length 10, weight 0.1) -> xp in Bu
    for (int idx = t; idx < Pp * C_; idx += 256) {
        const int p = idx / C_, c = idx - p * C_;
        const int s = (p * Lw) / Pp;               // {0,9,18,27,36,45,54}
        float acc = 0.f;
        #pragma unroll
        for (int j = 0; j < 10; ++j) acc += xw[c][s + j];
        Bu[idx] = acc * 0.1f;                      // xp(p,c) = Bu[p*96+c]
    }
    __syncthreads();

    // P2: gk = xp@Mk + bk2 (wave0+), gq = xp@Mq + bq2, bias dots on spare lanes
    if (t < 192) {
        const int which = (t >= C_) ? 1 : 0;
        const int cp = t - which * C_;
        const float* __restrict__ M = which ? Mq : Mk;
        float acc[Pp] = {};
        #pragma unroll 2
        for (int c4 = 0; c4 < 24; ++c4) {
            float4 xq[Pp];
            #pragma unroll
            for (int p = 0; p < Pp; ++p)
                xq[p] = *reinterpret_cast<const float4*>(&Bu[p * C_ + 4 * c4]);
            const float m0 = M[(4 * c4 + 0) * C_ + cp];
            const float m1 = M[(4 * c4 + 1) * C_ + cp];
            const float m2 = M[(4 * c4 + 2) * C_ + cp];
            const float m3 = M[(4 * c4 + 3) * C_ + cp];
            #pragma unroll
            for (int p = 0; p < Pp; ++p) {
                acc[p] = fmaf(xq[p].x, m0, acc[p]);
                acc[p] = fmaf(xq[p].y, m1, acc[p]);
                acc[p] = fmaf(xq[p].z, m2, acc[p]);
                acc[p] = fmaf(xq[p].w, m3, acc[p]);
            }
        }
        const float b2 = (which ? bq2 : bk2)[cp];
        #pragma unroll
        for (int p = 0; p < Pp; ++p) gkq[which][p][cp] = acc[p] + b2;
    } else if (t < 192 + 14) {
        const int j = t - 192;                     // 0..13
        const int p = j % 7;
        const float* u = (j < 7) ? uk : uq;
        float acc = 0.f;
        for (int c = 0; c < C_; ++c) acc = fmaf(Bu[p * C_ + c], u[c], acc);
        if (j < 7) bkd[p] = acc + scal[0]; else bqd[p] = acc + scal[1];
    }
    __syncthreads();

    // P3: k-logits, p-aligned waves (2 rounds), softmax over l in-register -> attn in Bu
    {
        const int l = t & 63, w = t >> 6;
        #pragma unroll
        for (int rnd = 0; rnd < 2; ++rnd) {
            const int p = rnd ? (4 + w) : w;
            if (rnd == 0 || w < 3) {
                float acc = 0.f;
                #pragma unroll 4
                for (int c4 = 0; c4 < 24; ++c4) {
                    const float4 g4 = *reinterpret_cast<const float4*>(&gkq[0][p][4 * c4]);
                    acc = fmaf(xw[4 * c4 + 0][l], g4.x, acc);
                    acc = fmaf(xw[4 * c4 + 1][l], g4.y, acc);
                    acc = fmaf(xw[4 * c4 + 2][l], g4.z, acc);
                    acc = fmaf(xw[4 * c4 + 3][l], g4.w, acc);
                }
                const float v = acc + bkd[p];
                float mx = v;
                #pragma unroll
                for (int off = 32; off; off >>= 1) mx = fmaxf(mx, __shfl_xor(mx, off));
                const float e = __expf(v - mx);
                float s = e;
                #pragma unroll
                for (int off = 32; off; off >>= 1) s += __shfl_xor(s, off);
                Bu[p * Lw + l] = e / s;            // attn(p,l)  (xp is dead)
            }
        }
    }
    __syncthreads();

    // P4: xv = attn @ xw^T  [7][96] -> Du  (full 256 threads, b128 attn broadcasts)
    for (int idx = t; idx < Pp * C_; idx += 256) {
        const int p = idx / C_, c = idx - p * C_;
        float acc = 0.f;
        #pragma unroll 4
        for (int l4 = 0; l4 < 16; ++l4) {
            const float4 a4 = *reinterpret_cast<const float4*>(&Bu[p * Lw + 4 * l4]);
            acc = fmaf(a4.x, xw[c][4 * l4 + 0], acc);
            acc = fmaf(a4.y, xw[c][4 * l4 + 1], acc);
            acc = fmaf(a4.z, xw[c][4 * l4 + 2], acc);
            acc = fmaf(a4.w, xw[c][4 * l4 + 3], acc);
        }
        Du[idx] = acc;                             // xv(p,c)
    }
    __syncthreads();

    // P5: avT[o][p] = xv[p]·Wv[o] + bv[o] -> Bu (attn dead; Wv rows read direct)
    for (int idx = t; idx < Pp * C_; idx += 256) {
        const int p = idx / C_, o = idx - p * C_;
        float acc = 0.f;
        #pragma unroll 4
        for (int c4 = 0; c4 < 24; ++c4) {
            const float4 v4 = *reinterpret_cast<const float4*>(&Du[p * C_ + 4 * c4]);
            const float4 w4 = *reinterpret_cast<const float4*>(&Wv[o * C_ + 4 * c4]);
            acc = fmaf(v4.x, w4.x, acc);
            acc = fmaf(v4.y, w4.y, acc);
            acc = fmaf(v4.z, w4.z, acc);
            acc = fmaf(v4.w, w4.w, acc);
        }
        Bu[o * 8 + p] = acc + bv[o];               // avT(o,p)
    }
    __syncthreads();

    // P6a: q-logits, p-aligned waves -> qraw in Du (xv dead)
    {
        const int l = t & 63, w = t >> 6;
        #pragma unroll
        for (int rnd = 0; rnd < 2; ++rnd) {
            const int p = rnd ? (4 + w) : w;
            if (rnd == 0 || w < 3) {
                float acc = 0.f;
                #pragma unroll 4
                for (int c4 = 0; c4 < 24; ++c4) {
                    const float4 g4 = *reinterpret_cast<const float4*>(&gkq[1][p][4 * c4]);
                    acc = fmaf(xw[4 * c4 + 0][l], g4.x, acc);
                    acc = fmaf(xw[4 * c4 + 1][l], g4.y, acc);
                    acc = fmaf(xw[4 * c4 + 2][l], g4.z, acc);
                    acc = fmaf(xw[4 * c4 + 3][l], g4.w, acc);
                }
                Du[l * 9 + p] = acc + bqd[p];      // qraw(l,p)
            }
        }
    }
    __syncthreads();

    // P6b: per-token softmax over p, in place
    if (t < 64) {
        float vv[Pp];
        float mx = -1e30f;
        #pragma unroll
        for (int p = 0; p < Pp; ++p) { vv[p] = Du[t * 9 + p]; mx = fmaxf(mx, vv[p]); }
        float s = 0.f;
        #pragma unroll
        for (int p = 0; p < Pp; ++p) { vv[p] = __expf(vv[p] - mx); s += vv[p]; }
        const float inv = 1.f / s;
        #pragma unroll
        for (int p = 0; p < Pp; ++p) Du[t * 9 + p] = vv[p] * inv;
    }
    __syncthreads();

    // P7: f = q_attn @ agent_v, scatter to out (avT b128 broadcasts, o wave-uniform)
    {
        const int l = t & 63, g = t >> 6;
        float qa[Pp];
        #pragma unroll
        for (int p = 0; p < Pp; ++p) qa[p] = Du[l * 9 + p];
        const int dh = l >> 3, dw = l & 7;
        const int obase = b * C_ * HWp + (h0 + dh) * Wimg + (w0 + dw);
        #pragma unroll 4
        for (int j = 0; j < 24; ++j) {
            const int o = g + 4 * j;
            const float4 a0 = *reinterpret_cast<const float4*>(&Bu[o * 8]);
            const float4 a1 = *reinterpret_cast<const float4*>(&Bu[o * 8 + 4]);
            float acc = qa[0] * a0.x;
            acc = fmaf(qa[1], a0.y, acc);
            acc = fmaf(qa[2], a0.z, acc);
            acc = fmaf(qa[3], a0.w, acc);
            acc = fmaf(qa[4], a1.x, acc);
            acc = fmaf(qa[5], a1.y, acc);
            acc = fmaf(qa[6], a1.z, acc);
            out[obase + o * HWp] = acc;
        }
    }
}

// ---------------- launch ----------------

extern "C" void kernel_launch(void* const* d_in, const int* in_sizes, int n_in,
                              void* d_out, int out_size, void* d_ws, size_t ws_size,
                              hipStream_t stream)
{
    const float* x  = (const float*)d_in[0];
    const float* Wv = (const float*)d_in[1];
    const float* bv = (const float*)d_in[2];
    const float* Wq = (const float*)d_in[3];
    const float* bq = (const float*)d_in[4];
    const float* Wk = (const float*)d_in[5];
    const float* bk = (const float*)d_in[6];
    float* out = (float*)d_out;

    float* ws   = (float*)d_ws;
    float* Mk   = ws;                 // 9216
    float* Mq   = ws + 9216;          // 9216
    float* uk   = ws + 18432;         // 96
    float* uq   = ws + 18528;         // 96
    float* bk2  = ws + 18624;         // 96
    float* bq2  = ws + 18720;         // 96
    float* scal = ws + 18816;         // 2

    hipLaunchKernelGGL(precompute_mats, dim3(C_), dim3(C_), 0, stream,
                       Wq, Wk, Mk, Mq);
    hipLaunchKernelGGL(precompute_vecs, dim3(1), dim3(C_), 0, stream,
                       Wq, Wk, bq, bk, uk, uq, bk2, bq2, scal);
    hipLaunchKernelGGL(camixer_main, dim3(8 * NWIN * NWIN), dim3(256), 0, stream,
                       x, Wv, bv, Mk, Mq, uk, uq, bk2, bq2, scal, out);
}